// Round 7
// baseline (93.702 us; speedup 1.0000x reference)
//
#include <hip/hip_runtime.h>
#include <hip/hip_bf16.h>
#include <stdint.h>

#define BATCH 2
#define NPTS  2048
#define CIN   64
#define COUT  64
#define NCELL 9

// knorm = 315 / (64*pi*0.1^9)
#define KNORM 1.5666851e9f
#define R2 0.01f

typedef __attribute__((ext_vector_type(8))) __bf16 bf16x8;
typedef __attribute__((ext_vector_type(4))) float  f32x4;

union B8 { uint4 u; bf16x8 v; };

static __device__ __forceinline__ unsigned pk2(float a, float b) {
    union { __hip_bfloat162 h; unsigned u; } cv;
    cv.h = __float22bfloat162_rn(make_float2(a, b));
    return cv.u;
}

// ---------------------------------------------------------------------------
// Workspace:
//   posT  float2[B*N]                    32 KB
//   dC    bf16  [B][C][N]  (c-major)    512 KB   (L2-resident)
//   WB    bf16  [9][2ks][4ob][64][8]     72 KB   -- GEMM2 B pre-swizzled frags
// ---------------------------------------------------------------------------

__global__ __launch_bounds__(256) void prep_kernel(
    const float* __restrict__ locs, const float* __restrict__ data,
    const float* __restrict__ density, const float* __restrict__ weight,
    const float* __restrict__ bias,
    float2* __restrict__ posT, uint16_t* __restrict__ dC,
    uint16_t* __restrict__ WB, float* __restrict__ out)
{
    const int tid = threadIdx.x;
    const int g = blockIdx.x;
    if (g < 256) {
        // dC[b][c][j] = bf16( data / (invmass * density) )
        int e = g * 256 + tid;             // 4 j each
        int j4 = e & 511, bc = e >> 9;
        int b = bc >> 6;
        float4 dv = *(const float4*)(data + bc * 2048 + j4 * 4);
        float4 de = *(const float4*)(density + b * 2048 + j4 * 4);
        int jb = (b * 2048 + j4 * 4) * 3 + 2;
        float m0 = locs[jb], m1 = locs[jb + 3], m2 = locs[jb + 6], m3 = locs[jb + 9];
        float v0 = dv.x / (m0 * de.x);
        float v1 = dv.y / (m1 * de.y);
        float v2 = dv.z / (m2 * de.z);
        float v3 = dv.w / (m3 * de.w);
        *(uint2*)(dC + bc * 2048 + j4 * 4) = make_uint2(pk2(v0, v1), pk2(v2, v3));
    } else if (g < 272) {
        int jj = (g - 256) * 256 + tid;
        posT[jj] = make_float2(locs[jj * 3], locs[jj * 3 + 1]);
    } else if (g < 272 + NCELL) {
        // WB[cell][ks][ob][lane][jj]: o = ob*16 + (lane&15), c = ks*32 + quad*8 + jj
        int cell = g - 272;
        for (int it = 0; it < 16; it++) {
            int e = it * 256 + tid;
            int ks = e >> 11, ob = (e >> 9) & 3, lane = (e >> 3) & 63, jj = e & 7;
            int o = ob * 16 + (lane & 15);
            int c = ks * 32 + ((lane >> 4) & 3) * 8 + jj;
            union { __hip_bfloat16 h; uint16_t u; } cv;
            cv.h = __float2bfloat16(weight[(o * 64 + c) * 9 + cell]);
            WB[cell * 4096 + e] = cv.u;
        }
    } else {
        // out[b][o][i] = bias[o]  (atomic accumulation target)
        const int gb = g - (272 + NCELL);
#pragma unroll
        for (int r = 0; r < 2; r++) {
            int e4 = (gb * 512 + r * 256 + tid) * 4;
            float bv = bias[(e4 >> 11) & 63];
            *(float4*)(out + e4) = make_float4(bv, bv, bv, bv);
        }
    }
}

// ---------------------------------------------------------------------------
// Fused conv, barrier-free K-loop.
// Block = one 16-i tile x one j-half; wave w handles ALL 9 cells over chunks
// n === w (mod 4) of the half (8 chunks of 32 j). No LDS staging: B-frags
// (dcoef) read directly from L2-hot dC with 1-deep register prefetch.
// GEMM2 per-wave (private LDS transpose slice), one final barrier for the
// 4-wave reduce, then 4 fp32 atomics/thread into bias-initialized out.
// ---------------------------------------------------------------------------
__global__ __launch_bounds__(256, 2) void conv_kernel(
    const float2* __restrict__ posT, const uint16_t* __restrict__ dC,
    const uint16_t* __restrict__ WB, float* __restrict__ out)
{
    __shared__ float sft[4][16 * 68];

    const int tid  = threadIdx.x;
    const int lane = tid & 63;
    const int wid  = tid >> 6;
    const int cl   = lane & 15;
    const int quad = lane >> 4;
    const int bx   = blockIdx.x;
    const int jh   = bx & 1;                  // j-half
    const int b    = bx >> 8;
    const int i0   = ((bx >> 1) & 127) * 16;

    const float2 pI = posT[b * 2048 + i0 + cl];

    f32x4 acc[NCELL][4];
#pragma unroll
    for (int k = 0; k < NCELL; k++)
#pragma unroll
        for (int nb = 0; nb < 4; nb++) acc[k][nb] = (f32x4){0.f, 0.f, 0.f, 0.f};

    // B-frag row bases: element (c = nb*16+cl, j = jbase + quad*8 + jj)
    const uint16_t* rb0 = dC + ((b * 64 +  0 + cl) * 2048) + jh * 1024 + wid * 32 + quad * 8;
    const uint16_t* rb1 = rb0 + 16 * 2048;
    const uint16_t* rb2 = rb0 + 32 * 2048;
    const uint16_t* rb3 = rb0 + 48 * 2048;
    const float2* pjb = posT + b * 2048 + jh * 1024 + wid * 32 + quad * 8;

    B8 bfc[4];
    bfc[0].u = *(const uint4*)rb0;
    bfc[1].u = *(const uint4*)rb1;
    bfc[2].u = *(const uint4*)rb2;
    bfc[3].u = *(const uint4*)rb3;

#pragma unroll
    for (int t = 0; t < 8; t++) {
        B8 bfn[4];
        if (t < 7) {                          // prefetch next chunk's B-frags
            bfn[0].u = *(const uint4*)(rb0 + (t + 1) * 128);
            bfn[1].u = *(const uint4*)(rb1 + (t + 1) * 128);
            bfn[2].u = *(const uint4*)(rb2 + (t + 1) * 128);
            bfn[3].u = *(const uint4*)(rb3 + (t + 1) * 128);
        }

        // my 8 pair geometries (pos from L1: 4 lanes/quad share lines)
        const float4* pp = (const float4*)(pjb + t * 128);
        float4 q0 = pp[0], q1 = pp[1], q2 = pp[2], q3 = pp[3];
        float dyv[8], ru0[8], ru1[8], ru2[8];
        {
            float dxv[8];
            dxv[0] = pI.x - q0.x; dyv[0] = pI.y - q0.y;
            dxv[1] = pI.x - q0.z; dyv[1] = pI.y - q0.w;
            dxv[2] = pI.x - q1.x; dyv[2] = pI.y - q1.y;
            dxv[3] = pI.x - q1.z; dyv[3] = pI.y - q1.w;
            dxv[4] = pI.x - q2.x; dyv[4] = pI.y - q2.y;
            dxv[5] = pI.x - q2.z; dyv[5] = pI.y - q2.w;
            dxv[6] = pI.x - q3.x; dyv[6] = pI.y - q3.y;
            dxv[7] = pI.x - q3.z; dyv[7] = pI.y - q3.w;
#pragma unroll
            for (int p = 0; p < 8; p++) {
                float a0 = dxv[p] - 0.05f;
                float a1 = dxv[p];
                float a2 = dxv[p] + 0.05f;
                ru0[p] = fmaf(-a0, a0, R2);   // R2 - ax^2, reused by 3 cells
                ru1[p] = fmaf(-a1, a1, R2);
                ru2[p] = fmaf(-a2, a2, R2);
            }
        }

#pragma unroll
        for (int k = 0; k < NCELL; k++) {
            const float oy = (float)(k % 3 - 1) * 0.05f;
            float w[8];
#pragma unroll
            for (int p = 0; p < 8; p++) {
                float ru = (k < 3) ? ru0[p] : (k < 6) ? ru1[p] : ru2[p];
                float c  = dyv[p] + oy;
                float tt = fmaf(-c, c, ru);
                float mt = fmaxf(tt, 0.0f);
                w[p] = (mt * mt) * (mt * KNORM);
            }
            B8 af;
            af.u = make_uint4(pk2(w[0], w[1]), pk2(w[2], w[3]),
                              pk2(w[4], w[5]), pk2(w[6], w[7]));
#pragma unroll
            for (int nb = 0; nb < 4; nb++)
                acc[k][nb] = __builtin_amdgcn_mfma_f32_16x16x32_bf16(
                    af.v, bfc[nb].v, acc[k][nb], 0, 0, 0);
        }

        if (t < 7) {
            bfc[0] = bfn[0]; bfc[1] = bfn[1];
            bfc[2] = bfn[2]; bfc[3] = bfn[3];
        }
    }

    // ---- GEMM2 per wave: 16i x 64o partial over own j-subset ---------------
    float* scr = &sft[wid][0];
    f32x4 acc2[4];
#pragma unroll
    for (int ob = 0; ob < 4; ob++) acc2[ob] = (f32x4){0.f, 0.f, 0.f, 0.f};

#pragma unroll
    for (int k = 0; k < NCELL; k++) {
        // C-frag (row=i=quad*4+r, col=c=nb*16+cl) -> scr[i][c]
#pragma unroll
        for (int nb = 0; nb < 4; nb++)
#pragma unroll
            for (int r = 0; r < 4; r++)
                scr[(quad * 4 + r) * 68 + nb * 16 + cl] = acc[k][nb][r];
        // A-frags (m=i=cl, k'=c=quad*8+jj); in-wave LDS ordering via lgkmcnt
#pragma unroll
        for (int ks = 0; ks < 2; ks++) {
            const float* fp = &scr[cl * 68 + ks * 32 + quad * 8];
            float4 lo = *(const float4*)fp;
            float4 hi = *(const float4*)(fp + 4);
            B8 af;
            af.u = make_uint4(pk2(lo.x, lo.y), pk2(lo.z, lo.w),
                              pk2(hi.x, hi.y), pk2(hi.z, hi.w));
#pragma unroll
            for (int ob = 0; ob < 4; ob++) {
                B8 wf;
                wf.u = *(const uint4*)(WB + k * 4096 + (ks * 4 + ob) * 512 + lane * 8);
                acc2[ob] = __builtin_amdgcn_mfma_f32_16x16x32_bf16(
                    af.v, wf.v, acc2[ob], 0, 0, 0);
            }
        }
    }

    // acc2 C-frag (row=i=quad*4+r, col o = ob*16+cl) -> scr[i][o]
#pragma unroll
    for (int ob = 0; ob < 4; ob++)
#pragma unroll
        for (int r = 0; r < 4; r++)
            scr[(quad * 4 + r) * 68 + ob * 16 + cl] = acc2[ob][r];
    __syncthreads();

    // reduce the 4 wave slices; 4 atomics/thread into out (2-way j contention)
    {
        const int i  = tid & 15;
        const int og = tid >> 4;              // 16 groups of 4 consecutive o
        float4 s0 = *(const float4*)&sft[0][i * 68 + og * 4];
        float4 s1 = *(const float4*)&sft[1][i * 68 + og * 4];
        float4 s2 = *(const float4*)&sft[2][i * 68 + og * 4];
        float4 s3 = *(const float4*)&sft[3][i * 68 + og * 4];
        float v0 = s0.x + s1.x + s2.x + s3.x;
        float v1 = s0.y + s1.y + s2.y + s3.y;
        float v2 = s0.z + s1.z + s2.z + s3.z;
        float v3 = s0.w + s1.w + s2.w + s3.w;
        float* op = out + (b * 64 + og * 4) * 2048 + i0 + i;
        unsafeAtomicAdd(op + 0 * 2048, v0);
        unsafeAtomicAdd(op + 1 * 2048, v1);
        unsafeAtomicAdd(op + 2 * 2048, v2);
        unsafeAtomicAdd(op + 3 * 2048, v3);
    }
}

extern "C" void kernel_launch(void* const* d_in, const int* in_sizes, int n_in,
                              void* d_out, int out_size, void* d_ws, size_t ws_size,
                              hipStream_t stream)
{
    const float* locs    = (const float*)d_in[0];   // (B, N, 3)
    const float* data    = (const float*)d_in[1];   // (B, CIN, N)
    const float* density = (const float*)d_in[2];   // (B, N)
    const float* weight  = (const float*)d_in[3];   // (COUT, CIN, 9)
    const float* bias    = (const float*)d_in[4];   // (COUT,)
    float* out = (float*)d_out;                     // (B, COUT, N)

    float2*   posT = (float2*)d_ws;                             // 32768 B
    uint16_t* dC   = (uint16_t*)((char*)d_ws + 32768);          // 524288 B
    uint16_t* WB   = (uint16_t*)((char*)d_ws + 32768 + 524288); // 73728 B

    prep_kernel<<<272 + NCELL + 128, 256, 0, stream>>>(
        locs, data, density, weight, bias, posT, dC, WB, out);
    conv_kernel<<<BATCH * 128 * 2, 256, 0, stream>>>(posT, dC, WB, out);
}